// Round 17
// baseline (317.063 us; speedup 1.0000x reference)
//
#include <hip/hip_runtime.h>
#include <hip/hip_bf16.h>
#include <math.h>

constexpr int kB = 16;
constexpr int kS = 256;
constexpr int kT = 1024;
constexpr int kM = 5151;
constexpr int kH = 256;
constexpr int kG = 16;                   // t-chunks (inside k_scan)
constexpr int kL = 64;                   // t's per chunk
constexpr int kJW = 84;                  // ceil(M/64) j-waves
constexpr int kJT = 16;                  // j per res3 block
constexpr int kRB = 322;                 // ceil(M/16) res3 blocks
constexpr float kSig = 1442.6950408889634f; // 1000 * log2(e)
constexpr float kAiS = 14.426950408889634f; // kSig / 100 (per alpha-index)

constexpr int OFF_BOUT = 0;
constexpr int OFF_DENS = kB * kT;                 // 16384
constexpr int OFF_M    = OFF_DENS + kB * kM;      // 98800
constexpr int OFF_IS   = OFF_M + kB * kT;         // 115184
constexpr int OFF_MESH = OFF_IS + kB * kM;        // 197600

// workspace layout (float-slot offsets). ws_size = 256 MiB (proven by harness poison).
constexpr int WS_TAB  = 0;        // 1654784 bf16 = 827392 float slots
constexpr int WS_ISF  = 3489280;  // 82416 fp32   -> end 3571696
constexpr int WS_PART = 3571712;  // 1376256 bf16 -> end 4259840
constexpr int WS_DENS = 4259840;  // 5376
constexpr int WS_DENSP= 4265216;  // 5376 (end 4270592 floats = 17.1 MB << 256 MiB)

__device__ __forceinline__ float exp2_fast(float x){ return __builtin_amdgcn_exp2f(x); }
__device__ __forceinline__ float rcp_fast(float x){ return __builtin_amdgcn_rcpf(x); }
// single-wave LDS fence: DS-op drain + compiler reorder barrier, but does NOT
// drain vmcnt — prefetched global loads stay in flight.
__device__ __forceinline__ void wave_lds_fence(){
    asm volatile("s_waitcnt lgkmcnt(0)" ::: "memory");
}

// ---- sigmoid table: WU[b][ai][t] = sigmoid((h[b][t] - ai/100) * 1000), bf16.
__global__ __launch_bounds__(256) void k_tab(const float* __restrict__ dec,
        __hip_bfloat16* __restrict__ TAB){
    int t  = blockIdx.x * 256 + threadIdx.x;   // grid.x = 4
    int ai = blockIdx.y;                        // 101
    int b  = blockIdx.z;                        // 16
    float hts = dec[b * kT + t] * kSig;
    float wu = rcp_fast(1.f + exp2_fast(fmaf((float)ai, kAiS, -hts)));
    TAB[(size_t)(b * 101 + ai) * kT + t] = __float2bfloat16(wu);
}

// ---- fully fused density MLP: x0-init + 3 residual layers + density dot.
// Block = 128 threads = 2 waves, 16 j per block (8 j-rows per wave, exclusive
// ownership -> NO barriers; lgkmcnt fences only). W read from global (L2) with
// EXPLICIT register double-buffering: load group g+1 while computing group g
// (the k_scan-proven pattern the compiler won't do on its own). 128 FMA per
// 4-k group (~256 issue cyc) covers L2 latency at depth 2.
__global__ __launch_bounds__(128) void k_res3(const float* __restrict__ mesh,
        const float* __restrict__ Win, const float* __restrict__ bin,
        const float* __restrict__ Wr, const float* __restrict__ br,
        const float* __restrict__ Wout, float* __restrict__ dens_pre){
    __shared__ float xL[kJT * 264];   // [j][k], stride 264 (16B-aligned, 16.9 KB)
    int t = threadIdx.x;
    int og = t & 63;                  // o = og*4 .. og*4+3
    int jg = t >> 6;                  // wave 0/1: rows jg*8 .. jg*8+7
    int jb = blockIdx.x * kJT;
    int o0 = og * 4;
    int r0 = jg * 8;
    float be[8], al[8];
    #pragma unroll
    for (int i = 0; i < 8; ++i){
        int jglob = jb + r0 + i;
        bool v = jglob < kM;
        be[i] = v ? mesh[2*jglob]   : 0.f;
        al[i] = v ? mesh[2*jglob+1] : 0.f;
    }
    // x0 = relu(mesh @ Win + bin) — write own 8x4 cells
    {
        float4 w0 = *(const float4*)&Win[o0];
        float4 w1 = *(const float4*)&Win[kH + o0];
        float4 b0 = *(const float4*)&bin[o0];
        #pragma unroll
        for (int i = 0; i < 8; ++i){
            float4 x;
            x.x = fmaxf(fmaf(be[i], w0.x, fmaf(al[i], w1.x, b0.x)), 0.f);
            x.y = fmaxf(fmaf(be[i], w0.y, fmaf(al[i], w1.y, b0.y)), 0.f);
            x.z = fmaxf(fmaf(be[i], w0.z, fmaf(al[i], w1.z, b0.z)), 0.f);
            x.w = fmaxf(fmaf(be[i], w0.w, fmaf(al[i], w1.w, b0.w)), 0.f);
            *(float4*)&xL[(r0 + i) * 264 + o0] = x;
        }
    }
    wave_lds_fence();                 // own-wave writes visible to own-wave lanes
    for (int l = 0; l < 3; ++l){
        const float* W  = Wr + l * kH * kH;
        const float* bl = br + l * kH;
        float acc[8][4] = {};
        float4 wA[4], wB[4], xA[8], xB[8];
        auto loadG = [&](int k, float4* wb, float4* xb){
            #pragma unroll
            for (int kk = 0; kk < 4; ++kk)
                wb[kk] = *(const float4*)&W[(k + kk) * kH + o0];   // coalesced L2
            #pragma unroll
            for (int i = 0; i < 8; ++i)
                xb[i] = *(const float4*)&xL[(r0 + i) * 264 + k];   // broadcast LDS
        };
        auto computeG = [&](const float4* wb, const float4* xb){
            #pragma unroll
            for (int kk = 0; kk < 4; ++kk){
                float4 w = wb[kk];
                #pragma unroll
                for (int i = 0; i < 8; ++i){
                    float xs = kk == 0 ? xb[i].x : kk == 1 ? xb[i].y
                             : kk == 2 ? xb[i].z : xb[i].w;
                    acc[i][0] = fmaf(xs, w.x, acc[i][0]);
                    acc[i][1] = fmaf(xs, w.y, acc[i][1]);
                    acc[i][2] = fmaf(xs, w.z, acc[i][2]);
                    acc[i][3] = fmaf(xs, w.w, acc[i][3]);
                }
            }
        };
        loadG(0, wA, xA);
        #pragma unroll 1
        for (int k = 0; k < kH; k += 8){
            loadG(k + 4, wB, xB);                         // prefetch odd group
            computeG(wA, xA);
            loadG(k + 8 < kH ? k + 8 : kH - 8, wA, xA);   // prefetch next even
            computeG(wB, xB);
        }
        wave_lds_fence();             // all xL reads of this layer drained
        float4 bb = *(const float4*)&bl[o0];
        #pragma unroll
        for (int i = 0; i < 8; ++i){
            float4 xo = *(const float4*)&xL[(r0 + i) * 264 + o0];
            xo.x += fmaxf(acc[i][0] + bb.x, 0.f);
            xo.y += fmaxf(acc[i][1] + bb.y, 0.f);
            xo.z += fmaxf(acc[i][2] + bb.z, 0.f);
            xo.w += fmaxf(acc[i][3] + bb.w, 0.f);
            *(float4*)&xL[(r0 + i) * 264 + o0] = xo;
        }
        wave_lds_fence();             // writes visible before next layer's reads
    }
    // density logits: dot(x3[j], Wout) over own cells, wave shuffle-reduce
    float4 wo = *(const float4*)&Wout[o0];
    float p[8];
    #pragma unroll
    for (int i = 0; i < 8; ++i){
        float4 x = *(const float4*)&xL[(r0 + i) * 264 + o0];
        p[i] = fmaf(x.x, wo.x, fmaf(x.y, wo.y, fmaf(x.z, wo.z, x.w * wo.w)));
    }
    #pragma unroll
    for (int off = 32; off; off >>= 1){
        #pragma unroll
        for (int i = 0; i < 8; ++i) p[i] += __shfl_down(p[i], off, 64);
    }
    if (og == 0){
        #pragma unroll
        for (int i = 0; i < 8; ++i){
            int jglob = jb + r0 + i;
            if (jglob < kM) dens_pre[jglob] = p[i];
        }
    }
}

// ---- fused: encoder context (recomputed per block) + density sigmoid + initial states.
__global__ __launch_bounds__(256) void k_init(const float* __restrict__ enc_in,
        const float* __restrict__ mask, const float* __restrict__ Ws,
        const float* __restrict__ bs, const float* __restrict__ Wc,
        const float* __restrict__ mesh, const float* __restrict__ dens_pre,
        const float* __restrict__ bout, const float* __restrict__ Wm,
        const float* __restrict__ bm, const float* __restrict__ Wo,
        const float* __restrict__ bo, float* __restrict__ dens,
        float* __restrict__ isf, float* __restrict__ out){
    __shared__ float ctx_l[kH];
    __shared__ float w0s[kH], w1s[kH], w2s[kH], bcs[kH], wos[kH];
    int tid = threadIdx.x;
    int b = blockIdx.y;
    {
        float w0 = Ws[tid], w1 = Ws[kH + tid], bh = bs[tid];
        float acc = 0.f, msum = 0.f;
        const float* e = enc_in + b * kS * 2;
        const float* mk = mask + b * kS;
        #pragma unroll 4
        for (int s = 0; s < kS; ++s){
            float e0 = e[2*s], e1 = e[2*s+1], mm = mk[s];
            float v = fmaxf(fmaf(e0, w0, fmaf(e1, w1, bh)), 0.f);
            acc = fmaf(v, mm, acc);
            msum += mm;
        }
        ctx_l[tid] = acc / fmaxf(msum, 1.f);
    }
    __syncthreads();
    float cw = 0.f;
    #pragma unroll 8
    for (int k = 0; k < kH; ++k) cw = fmaf(ctx_l[k], Wc[k * kH + tid], cw);
    w0s[tid] = Wm[tid];
    w1s[tid] = Wm[kH + tid];
    w2s[tid] = Wm[2*kH + tid];
    bcs[tid] = bm[tid] + cw;
    wos[tid] = Wo[tid];
    __syncthreads();
    int j = blockIdx.x * 256 + tid;
    if (j >= kM) return;
    float d = 1.f / (1.f + expf(-(dens_pre[j] + bout[0])));
    if (b == 0) dens[j] = d;
    float be = mesh[2*j], al = mesh[2*j+1];
    float acc = 0.f;
    #pragma unroll 8
    for (int h = 0; h < kH; ++h){
        float pre = fmaf(be, w0s[h], fmaf(al, w1s[h], fmaf(d, w2s[h], bcs[h])));
        acc = fmaf(fmaxf(pre, 0.f), wos[h], acc);
    }
    float s = tanhf(acc + bo[0]);
    isf[b * kM + j] = s;
    out[OFF_IS + b * kM + j] = s;
}

__device__ __forceinline__ float bfhalf(unsigned int w, int odd){
    return __uint_as_float(odd ? (w & 0xffff0000u) : (w << 16));
}

// ---- single-pass relay scan. q = s+1; one relay step:
//   q' = w * fmaf(u, 2-q, q)   where u = WU[ai][t], w = WU[bi][t]  (wd = 1-w)
// Register double-buffer prefetch; single-wave blocks + lgkmcnt-only fences;
// XCD swizzle keeps each XCD's WU working set (2 b's, 414 KB) L2-resident.
__global__ __launch_bounds__(64) void k_scan(const float* __restrict__ mesh,
        const float* __restrict__ dens, const float* __restrict__ isf,
        const __hip_bfloat16* __restrict__ TAB,
        __hip_bfloat16* __restrict__ partials, float* __restrict__ out){
    __shared__ unsigned short cb[kL * 66];
    int L = threadIdx.x;
    int blk = blockIdx.x;                 // 0..1343
    int xcd = blk & 7;                    // round-robin XCD heuristic
    int i   = blk >> 3;                   // 0..167
    int b   = (xcd << 1) | (i >= kJW ? 1 : 0);   // 2 b's per XCD
    int jw  = (i >= kJW) ? i - kJW : i;
    int j = jw * 64 + L;
    bool valid = j < kM;
    int jj = valid ? j : 0;
    float d  = valid ? dens[j] : 0.f;
    float q  = valid ? isf[b * kM + j] + 1.f : 0.f;
    float be = mesh[2*jj], al = mesh[2*jj+1];
    int ai = __float2int_rn(al * 100.f);
    int bi = __float2int_rn(be * 100.f);
    const __hip_bfloat16* ra = TAB + (size_t)(b * 101 + ai) * kT;
    const __hip_bfloat16* rb = TAB + (size_t)(b * 101 + bi) * kT;
    if (valid){
        out[OFF_DENS + b * kM + j] = d;
        out[OFF_MESH + 2 * (b * kM + j)]     = be;
        out[OFF_MESH + 2 * (b * kM + j) + 1] = al;
    }
    size_t pbase = (size_t)(b * kJW + jw) * kT + L;

    unsigned int uaA[32], ubA[32], uaB[32], ubB[32];

    auto load_chunk = [&](int g, unsigned int* UA, unsigned int* UB){
        const uint4* pa = (const uint4*)(ra + g * kL);
        const uint4* pb = (const uint4*)(rb + g * kL);
        #pragma unroll
        for (int i2 = 0; i2 < 8; ++i2){
            uint4 va = pa[i2];
            UA[4*i2]=va.x; UA[4*i2+1]=va.y; UA[4*i2+2]=va.z; UA[4*i2+3]=va.w;
        }
        #pragma unroll
        for (int i2 = 0; i2 < 8; ++i2){
            uint4 vb = pb[i2];
            UB[4*i2]=vb.x; UB[4*i2+1]=vb.y; UB[4*i2+2]=vb.z; UB[4*i2+3]=vb.w;
        }
    };
    auto compute_chunk = [&](int g, const unsigned int* UA, const unsigned int* UB){
        #pragma unroll
        for (int t = 0; t < kL; ++t){
            float u = bfhalf(UA[t>>1], t & 1);
            float w = bfhalf(UB[t>>1], t & 1);
            q = w * fmaf(u, 2.f - q, q);                 // full relay step
            float v = fmaf(d, q, -d);                    // d*s = d*q - d
            cb[t * 66 + L] = (unsigned short)(__float_as_uint(v) >> 16);  // trunc bf16
        }
        wave_lds_fence();   // single-wave block: DS drain only, vmcnt stays in flight
        float a0 = 0.f, a1 = 0.f;
        const __hip_bfloat162* row = (const __hip_bfloat162*)&cb[L * 66];
        #pragma unroll
        for (int i2 = 0; i2 < 32; ++i2){
            float2 f = __bfloat1622float2(row[i2]);
            a0 += f.x; a1 += f.y;
        }
        partials[pbase + g * kL] = __float2bfloat16(a0 + a1);
        wave_lds_fence();   // reads done before next chunk overwrites cb
    };

    load_chunk(0, uaA, ubA);
    #pragma unroll 1
    for (int g = 0; g < kG; g += 2){
        load_chunk(g + 1, uaB, ubB);          // prefetch odd chunk
        compute_chunk(g, uaA, ubA);
        if (g + 2 < kG) load_chunk(g + 2, uaA, ubA);   // prefetch next even chunk
        compute_chunk(g + 1, uaB, ubB);
    }
}

// ---- finalize: per-block dsum; m = sum(partials)/dsum; b_out = hs*h + ms*m + mo
__global__ __launch_bounds__(256) void k_final(const __hip_bfloat16* __restrict__ partials,
        const float* __restrict__ dens, const float* __restrict__ dec,
        const float* __restrict__ hsr, const float* __restrict__ msr,
        const float* __restrict__ mor, float* __restrict__ out){
    __shared__ float red[4];
    int tid = threadIdx.x;
    int b = blockIdx.y;
    float ds = 0.f;
    for (int i = tid; i < kM; i += 256) ds += dens[i];
    #pragma unroll
    for (int off = 32; off; off >>= 1) ds += __shfl_down(ds, off, 64);
    if ((tid & 63) == 0) red[tid >> 6] = ds;
    __syncthreads();
    float dsum = red[0] + red[1] + red[2] + red[3];
    int t = blockIdx.x * 256 + tid;   // grid.x = 4
    float acc = 0.f;
    const __hip_bfloat16* p = partials + (size_t)b * kJW * kT + t;
    #pragma unroll 4
    for (int w = 0; w < kJW; ++w) acc += __bfloat162float(p[(size_t)w * kT]);
    float m = acc / dsum;
    float hscale = 10.f / (1.f + expf(-hsr[0]));
    float mscale = 10.f / (1.f + expf(-msr[0]));
    float moff   = -10.f + 20.f / (1.f + expf(-mor[0]));
    float h = dec[b * kT + t];
    out[OFF_M + b * kT + t]    = m;
    out[OFF_BOUT + b * kT + t] = fmaf(hscale, h, fmaf(mscale, m, moff));
}

extern "C" void kernel_launch(void* const* d_in, const int* in_sizes, int n_in,
                              void* d_out, int out_size, void* d_ws, size_t ws_size,
                              hipStream_t stream) {
    (void)in_sizes; (void)n_in; (void)out_size; (void)ws_size;
    const float* enc_in = (const float*)d_in[0];
    const float* dec    = (const float*)d_in[1];
    const float* mask   = (const float*)d_in[2];
    const float* mesh   = (const float*)d_in[3];
    const float* Win    = (const float*)d_in[4];
    const float* bin    = (const float*)d_in[5];
    const float* Wr     = (const float*)d_in[6];
    const float* br     = (const float*)d_in[7];
    const float* Wout   = (const float*)d_in[8];
    const float* bout   = (const float*)d_in[9];
    const float* Ws     = (const float*)d_in[10];
    const float* bs     = (const float*)d_in[11];
    const float* Wm     = (const float*)d_in[12];
    const float* Wc     = (const float*)d_in[13];
    const float* bm     = (const float*)d_in[14];
    const float* Wo     = (const float*)d_in[15];
    const float* bo     = (const float*)d_in[16];
    const float* hsr    = (const float*)d_in[17];
    const float* msr    = (const float*)d_in[18];
    const float* mor    = (const float*)d_in[19];
    float* out = (float*)d_out;

    float* ws = (float*)d_ws;
    __hip_bfloat16* TAB      = (__hip_bfloat16*)(ws + WS_TAB);
    float* isf   = ws + WS_ISF;
    __hip_bfloat16* partials = (__hip_bfloat16*)(ws + WS_PART);
    float* densv = ws + WS_DENS;
    float* densp = ws + WS_DENSP;

    k_tab   <<<dim3(4, 101, kB),  256, 0, stream>>>(dec, TAB);
    k_res3  <<<dim3(kRB),         128, 0, stream>>>(mesh, Win, bin, Wr, br, Wout, densp);
    k_init  <<<dim3(21, kB),      256, 0, stream>>>(enc_in, mask, Ws, bs, Wc, mesh, densp,
                                                    bout, Wm, bm, Wo, bo, densv, isf, out);
    k_scan  <<<dim3(kJW * kB),     64, 0, stream>>>(mesh, densv, isf, TAB, partials, out);
    k_final <<<dim3(4, kB),       256, 0, stream>>>(partials, densv, dec, hsr, msr, mor, out);
}

// Round 18
// 242.273 us; speedup vs baseline: 1.3087x; 1.3087x over previous
//
#include <hip/hip_runtime.h>
#include <hip/hip_bf16.h>
#include <math.h>

constexpr int kB = 16;
constexpr int kS = 256;
constexpr int kT = 1024;
constexpr int kM = 5151;
constexpr int kH = 256;
constexpr int kG = 16;                   // t-chunks (inside k_scan)
constexpr int kL = 64;                   // t's per chunk
constexpr int kJW = 84;                  // ceil(M/64) j-waves
constexpr int kJT = 8;                   // j per res3 block
constexpr int kRB = 644;                 // ceil(M/8) res3 blocks (2.5 blocks/CU)
constexpr float kSig = 1442.6950408889634f; // 1000 * log2(e)
constexpr float kAiS = 14.426950408889634f; // kSig / 100 (per alpha-index)

constexpr int OFF_BOUT = 0;
constexpr int OFF_DENS = kB * kT;                 // 16384
constexpr int OFF_M    = OFF_DENS + kB * kM;      // 98800
constexpr int OFF_IS   = OFF_M + kB * kT;         // 115184
constexpr int OFF_MESH = OFF_IS + kB * kM;        // 197600

// workspace layout (float-slot offsets). ws_size = 256 MiB (proven by harness poison).
constexpr int WS_TAB  = 0;        // 1654784 bf16 = 827392 float slots
constexpr int WS_ISF  = 3489280;  // 82416 fp32   -> end 3571696
constexpr int WS_PART = 3571712;  // 1376256 bf16 -> end 4259840
constexpr int WS_DENS = 4259840;  // 5376
constexpr int WS_DENSP= 4265216;  // 5376 (end 4270592 floats = 17.1 MB << 256 MiB)

__device__ __forceinline__ float exp2_fast(float x){ return __builtin_amdgcn_exp2f(x); }
__device__ __forceinline__ float rcp_fast(float x){ return __builtin_amdgcn_rcpf(x); }
// single-wave LDS fence: DS-op drain + compiler reorder barrier, but does NOT
// drain vmcnt — prefetched global loads stay in flight.
__device__ __forceinline__ void wave_lds_fence(){
    asm volatile("s_waitcnt lgkmcnt(0)" ::: "memory");
}

// ---- sigmoid table: WU[b][ai][t] = sigmoid((h[b][t] - ai/100) * 1000), bf16.
__global__ __launch_bounds__(256) void k_tab(const float* __restrict__ dec,
        __hip_bfloat16* __restrict__ TAB){
    int t  = blockIdx.x * 256 + threadIdx.x;   // grid.x = 4
    int ai = blockIdx.y;                        // 101
    int b  = blockIdx.z;                        // 16
    float hts = dec[b * kT + t] * kSig;
    float wu = rcp_fast(1.f + exp2_fast(fmaf((float)ai, kAiS, -hts)));
    TAB[(size_t)(b * 101 + ai) * kT + t] = __float2bfloat16(wu);
}

// ---- fully fused density MLP (R15 structure, 8 j/block for 2.5 blocks/CU):
// x0-init + 3 residual layers + density dot. Block 256 threads, thread =
// (jl = t&7, oo = t>>3): 8 outs o = oo*8..+7 for one j-column jl.
// Per-slab barrier W-staging; with >=2 blocks/CU the drain phases of one block
// overlap the FMA phases of the co-resident block (m114 mechanism).
__global__ __launch_bounds__(256) void k_res3(const float* __restrict__ mesh,
        const float* __restrict__ Win, const float* __restrict__ bin,
        const float* __restrict__ Wr, const float* __restrict__ br,
        const float* __restrict__ Wout, float* __restrict__ dens_pre){
    __shared__ float xL[256 * 8];     // 8 KB [k][j]
    __shared__ float Wsh[32 * 256];   // 32 KB [k][o] slab
    __shared__ float dred[256];
    __shared__ float beL[8], alL[8];
    int t = threadIdx.x;
    int jl = t & 7, oo = t >> 3;      // oo in 0..31, o = oo*8..+7
    int jb = blockIdx.x * kJT;
    int o0 = oo * 8;
    if (t < 8){
        int jg = jb + t;
        beL[t] = (jg < kM) ? mesh[2*jg]   : 0.f;
        alL[t] = (jg < kM) ? mesh[2*jg+1] : 0.f;
    }
    __syncthreads();
    // x0 = relu(mesh @ Win + bin)
    #pragma unroll
    for (int it = 0; it < 8; ++it){
        int lin = t + it * 256;
        int k = lin >> 3, j = lin & 7;
        xL[lin] = fmaxf(fmaf(beL[j], Win[k], fmaf(alL[j], Win[kH + k], bin[k])), 0.f);
    }
    for (int l = 0; l < 3; ++l){
        const float* W  = Wr + l * kH * kH;
        const float* bl = br + l * kH;
        float acc[8] = {};
        for (int ks = 0; ks < 8; ++ks){           // 32-row k-slabs
            __syncthreads();                      // xL ready / Wsh reuse safe
            const float4* Wg = (const float4*)(W + ks * 32 * kH);
            float4* Ws4 = (float4*)Wsh;
            #pragma unroll
            for (int it = 0; it < 8; ++it) Ws4[t + it * 256] = Wg[t + it * 256];
            __syncthreads();
            #pragma unroll 2
            for (int k = 0; k < 32; ++k){
                float xv = xL[(ks * 32 + k) * 8 + jl];
                const float4* wrow = (const float4*)&Wsh[k * 256 + o0];
                float4 w0 = wrow[0], w1 = wrow[1];
                acc[0] = fmaf(xv, w0.x, acc[0]); acc[1] = fmaf(xv, w0.y, acc[1]);
                acc[2] = fmaf(xv, w0.z, acc[2]); acc[3] = fmaf(xv, w0.w, acc[3]);
                acc[4] = fmaf(xv, w1.x, acc[4]); acc[5] = fmaf(xv, w1.y, acc[5]);
                acc[6] = fmaf(xv, w1.z, acc[6]); acc[7] = fmaf(xv, w1.w, acc[7]);
            }
        }
        __syncthreads();                          // all xL reads of this layer done
        #pragma unroll
        for (int i = 0; i < 8; ++i){              // residual update: own cells only
            int o = o0 + i;
            float xo = xL[o * 8 + jl];
            xL[o * 8 + jl] = xo + fmaxf(acc[i] + bl[o], 0.f);
        }
    }
    // density logits: dot(x3[j], Wout) — own cells, then cross-oo LDS reduce
    float p = 0.f;
    #pragma unroll
    for (int i = 0; i < 8; ++i){
        int o = o0 + i;
        p = fmaf(xL[o * 8 + jl], Wout[o], p);
    }
    dred[t] = p;                                  // t == oo*8 + jl
    __syncthreads();
    if (t < 8){
        float s = 0.f;
        #pragma unroll
        for (int ii = 0; ii < 32; ++ii) s += dred[ii * 8 + t];
        int jg = jb + t;
        if (jg < kM) dens_pre[jg] = s;
    }
}

// ---- fused: encoder context (recomputed per block) + density sigmoid + initial states.
__global__ __launch_bounds__(256) void k_init(const float* __restrict__ enc_in,
        const float* __restrict__ mask, const float* __restrict__ Ws,
        const float* __restrict__ bs, const float* __restrict__ Wc,
        const float* __restrict__ mesh, const float* __restrict__ dens_pre,
        const float* __restrict__ bout, const float* __restrict__ Wm,
        const float* __restrict__ bm, const float* __restrict__ Wo,
        const float* __restrict__ bo, float* __restrict__ dens,
        float* __restrict__ isf, float* __restrict__ out){
    __shared__ float ctx_l[kH];
    __shared__ float w0s[kH], w1s[kH], w2s[kH], bcs[kH], wos[kH];
    int tid = threadIdx.x;
    int b = blockIdx.y;
    {
        float w0 = Ws[tid], w1 = Ws[kH + tid], bh = bs[tid];
        float acc = 0.f, msum = 0.f;
        const float* e = enc_in + b * kS * 2;
        const float* mk = mask + b * kS;
        #pragma unroll 4
        for (int s = 0; s < kS; ++s){
            float e0 = e[2*s], e1 = e[2*s+1], mm = mk[s];
            float v = fmaxf(fmaf(e0, w0, fmaf(e1, w1, bh)), 0.f);
            acc = fmaf(v, mm, acc);
            msum += mm;
        }
        ctx_l[tid] = acc / fmaxf(msum, 1.f);
    }
    __syncthreads();
    float cw = 0.f;
    #pragma unroll 8
    for (int k = 0; k < kH; ++k) cw = fmaf(ctx_l[k], Wc[k * kH + tid], cw);
    w0s[tid] = Wm[tid];
    w1s[tid] = Wm[kH + tid];
    w2s[tid] = Wm[2*kH + tid];
    bcs[tid] = bm[tid] + cw;
    wos[tid] = Wo[tid];
    __syncthreads();
    int j = blockIdx.x * 256 + tid;
    if (j >= kM) return;
    float d = 1.f / (1.f + expf(-(dens_pre[j] + bout[0])));
    if (b == 0) dens[j] = d;
    float be = mesh[2*j], al = mesh[2*j+1];
    float acc = 0.f;
    #pragma unroll 8
    for (int h = 0; h < kH; ++h){
        float pre = fmaf(be, w0s[h], fmaf(al, w1s[h], fmaf(d, w2s[h], bcs[h])));
        acc = fmaf(fmaxf(pre, 0.f), wos[h], acc);
    }
    float s = tanhf(acc + bo[0]);
    isf[b * kM + j] = s;
    out[OFF_IS + b * kM + j] = s;
}

__device__ __forceinline__ float bfhalf(unsigned int w, int odd){
    return __uint_as_float(odd ? (w & 0xffff0000u) : (w << 16));
}

// ---- single-pass relay scan. q = s+1; one relay step:
//   q' = w * fmaf(u, 2-q, q)   where u = WU[ai][t], w = WU[bi][t]  (wd = 1-w)
// Register double-buffer prefetch; single-wave blocks + lgkmcnt-only fences;
// XCD swizzle keeps each XCD's WU working set (2 b's, 414 KB) L2-resident.
__global__ __launch_bounds__(64) void k_scan(const float* __restrict__ mesh,
        const float* __restrict__ dens, const float* __restrict__ isf,
        const __hip_bfloat16* __restrict__ TAB,
        __hip_bfloat16* __restrict__ partials, float* __restrict__ out){
    __shared__ unsigned short cb[kL * 66];
    int L = threadIdx.x;
    int blk = blockIdx.x;                 // 0..1343
    int xcd = blk & 7;                    // round-robin XCD heuristic
    int i   = blk >> 3;                   // 0..167
    int b   = (xcd << 1) | (i >= kJW ? 1 : 0);   // 2 b's per XCD
    int jw  = (i >= kJW) ? i - kJW : i;
    int j = jw * 64 + L;
    bool valid = j < kM;
    int jj = valid ? j : 0;
    float d  = valid ? dens[j] : 0.f;
    float q  = valid ? isf[b * kM + j] + 1.f : 0.f;
    float be = mesh[2*jj], al = mesh[2*jj+1];
    int ai = __float2int_rn(al * 100.f);
    int bi = __float2int_rn(be * 100.f);
    const __hip_bfloat16* ra = TAB + (size_t)(b * 101 + ai) * kT;
    const __hip_bfloat16* rb = TAB + (size_t)(b * 101 + bi) * kT;
    if (valid){
        out[OFF_DENS + b * kM + j] = d;
        out[OFF_MESH + 2 * (b * kM + j)]     = be;
        out[OFF_MESH + 2 * (b * kM + j) + 1] = al;
    }
    size_t pbase = (size_t)(b * kJW + jw) * kT + L;

    unsigned int uaA[32], ubA[32], uaB[32], ubB[32];

    auto load_chunk = [&](int g, unsigned int* UA, unsigned int* UB){
        const uint4* pa = (const uint4*)(ra + g * kL);
        const uint4* pb = (const uint4*)(rb + g * kL);
        #pragma unroll
        for (int i2 = 0; i2 < 8; ++i2){
            uint4 va = pa[i2];
            UA[4*i2]=va.x; UA[4*i2+1]=va.y; UA[4*i2+2]=va.z; UA[4*i2+3]=va.w;
        }
        #pragma unroll
        for (int i2 = 0; i2 < 8; ++i2){
            uint4 vb = pb[i2];
            UB[4*i2]=vb.x; UB[4*i2+1]=vb.y; UB[4*i2+2]=vb.z; UB[4*i2+3]=vb.w;
        }
    };
    auto compute_chunk = [&](int g, const unsigned int* UA, const unsigned int* UB){
        #pragma unroll
        for (int t = 0; t < kL; ++t){
            float u = bfhalf(UA[t>>1], t & 1);
            float w = bfhalf(UB[t>>1], t & 1);
            q = w * fmaf(u, 2.f - q, q);                 // full relay step
            float v = fmaf(d, q, -d);                    // d*s = d*q - d
            cb[t * 66 + L] = (unsigned short)(__float_as_uint(v) >> 16);  // trunc bf16
        }
        wave_lds_fence();   // single-wave block: DS drain only, vmcnt stays in flight
        float a0 = 0.f, a1 = 0.f;
        const __hip_bfloat162* row = (const __hip_bfloat162*)&cb[L * 66];
        #pragma unroll
        for (int i2 = 0; i2 < 32; ++i2){
            float2 f = __bfloat1622float2(row[i2]);
            a0 += f.x; a1 += f.y;
        }
        partials[pbase + g * kL] = __float2bfloat16(a0 + a1);
        wave_lds_fence();   // reads done before next chunk overwrites cb
    };

    load_chunk(0, uaA, ubA);
    #pragma unroll 1
    for (int g = 0; g < kG; g += 2){
        load_chunk(g + 1, uaB, ubB);          // prefetch odd chunk
        compute_chunk(g, uaA, ubA);
        if (g + 2 < kG) load_chunk(g + 2, uaA, ubA);   // prefetch next even chunk
        compute_chunk(g + 1, uaB, ubB);
    }
}

// ---- finalize: per-block dsum; m = sum(partials)/dsum; b_out = hs*h + ms*m + mo
__global__ __launch_bounds__(256) void k_final(const __hip_bfloat16* __restrict__ partials,
        const float* __restrict__ dens, const float* __restrict__ dec,
        const float* __restrict__ hsr, const float* __restrict__ msr,
        const float* __restrict__ mor, float* __restrict__ out){
    __shared__ float red[4];
    int tid = threadIdx.x;
    int b = blockIdx.y;
    float ds = 0.f;
    for (int i = tid; i < kM; i += 256) ds += dens[i];
    #pragma unroll
    for (int off = 32; off; off >>= 1) ds += __shfl_down(ds, off, 64);
    if ((tid & 63) == 0) red[tid >> 6] = ds;
    __syncthreads();
    float dsum = red[0] + red[1] + red[2] + red[3];
    int t = blockIdx.x * 256 + tid;   // grid.x = 4
    float acc = 0.f;
    const __hip_bfloat16* p = partials + (size_t)b * kJW * kT + t;
    #pragma unroll 4
    for (int w = 0; w < kJW; ++w) acc += __bfloat162float(p[(size_t)w * kT]);
    float m = acc / dsum;
    float hscale = 10.f / (1.f + expf(-hsr[0]));
    float mscale = 10.f / (1.f + expf(-msr[0]));
    float moff   = -10.f + 20.f / (1.f + expf(-mor[0]));
    float h = dec[b * kT + t];
    out[OFF_M + b * kT + t]    = m;
    out[OFF_BOUT + b * kT + t] = fmaf(hscale, h, fmaf(mscale, m, moff));
}

extern "C" void kernel_launch(void* const* d_in, const int* in_sizes, int n_in,
                              void* d_out, int out_size, void* d_ws, size_t ws_size,
                              hipStream_t stream) {
    (void)in_sizes; (void)n_in; (void)out_size; (void)ws_size;
    const float* enc_in = (const float*)d_in[0];
    const float* dec    = (const float*)d_in[1];
    const float* mask   = (const float*)d_in[2];
    const float* mesh   = (const float*)d_in[3];
    const float* Win    = (const float*)d_in[4];
    const float* bin    = (const float*)d_in[5];
    const float* Wr     = (const float*)d_in[6];
    const float* br     = (const float*)d_in[7];
    const float* Wout   = (const float*)d_in[8];
    const float* bout   = (const float*)d_in[9];
    const float* Ws     = (const float*)d_in[10];
    const float* bs     = (const float*)d_in[11];
    const float* Wm     = (const float*)d_in[12];
    const float* Wc     = (const float*)d_in[13];
    const float* bm     = (const float*)d_in[14];
    const float* Wo     = (const float*)d_in[15];
    const float* bo     = (const float*)d_in[16];
    const float* hsr    = (const float*)d_in[17];
    const float* msr    = (const float*)d_in[18];
    const float* mor    = (const float*)d_in[19];
    float* out = (float*)d_out;

    float* ws = (float*)d_ws;
    __hip_bfloat16* TAB      = (__hip_bfloat16*)(ws + WS_TAB);
    float* isf   = ws + WS_ISF;
    __hip_bfloat16* partials = (__hip_bfloat16*)(ws + WS_PART);
    float* densv = ws + WS_DENS;
    float* densp = ws + WS_DENSP;

    k_tab   <<<dim3(4, 101, kB),  256, 0, stream>>>(dec, TAB);
    k_res3  <<<dim3(kRB),         256, 0, stream>>>(mesh, Win, bin, Wr, br, Wout, densp);
    k_init  <<<dim3(21, kB),      256, 0, stream>>>(enc_in, mask, Ws, bs, Wc, mesh, densp,
                                                    bout, Wm, bm, Wo, bo, densv, isf, out);
    k_scan  <<<dim3(kJW * kB),     64, 0, stream>>>(mesh, densv, isf, TAB, partials, out);
    k_final <<<dim3(4, kB),       256, 0, stream>>>(partials, densv, dec, hsr, msr, mor, out);
}